// Round 1
// baseline (895.728 us; speedup 1.0000x reference)
//
#include <hip/hip_runtime.h>

// Tanh-RNN: B=8192, T=2048, I=2, H=20, then FC(H->1) on last h.
// Scheme: 8 lanes per batch row (1024 waves total = 1 wave/SIMD on 256 CUs).
// Lane g in [0,8) owns output indices j = 3g..3g+2 (H padded 20->24; garbage
// lanes compute zeros). W_hh rows live in per-lane registers (60 VGPRs).
// h exchange between the 8 lanes of a row via __shfl broadcasts (no LDS,
// no __syncthreads anywhere). x read as coalesced float2 per 8-step chunk,
// broadcast by shfl, so HBM traffic is exactly one pass over x (134 MB).

#define T_STEPS 2048
#define B_ROWS  8192

__device__ __forceinline__ float tanh_fast(float a) {
    // tanh(a) = 1 - 2/(exp(2a)+1); exp(2a) = exp2(a * 2*log2(e))
    float e = __builtin_amdgcn_exp2f(a * 2.8853900817779268f);
    float r = __builtin_amdgcn_rcpf(e + 1.0f);   // ~1 ulp, fine vs 2% threshold
    return fmaf(-2.0f, r, 1.0f);
    // a=0 -> 0; a->+inf: e=inf, r=0 -> +1; a->-inf: e=0, r=1 -> -1.
}

__global__ __launch_bounds__(256) void rnn_fused(
    const float* __restrict__ x,      // [B, T, 2]
    const float* __restrict__ W_ih,   // [20, 2]
    const float* __restrict__ W_hh,   // [20, 20]
    const float* __restrict__ b_ih,   // [20]
    const float* __restrict__ b_hh,   // [20]
    const float* __restrict__ fc_w,   // [1, 20]
    const float* __restrict__ fc_b,   // [1]
    float* __restrict__ out)          // [8192] out, then [8192*20] h_state
{
    const int tid     = blockIdx.x * blockDim.x + threadIdx.x;
    const int lane    = threadIdx.x & 63;
    const int g       = lane & 7;            // j-group within the row's octet
    const int rowbase = lane & 56;           // first lane of this row's octet
    const int row     = (tid >> 6) * 8 + ((lane >> 3) & 7);

    // ---- per-lane constants (j = 3g+jj; zero for padded j >= 20) ----
    float Wc[3][20];
    float wi0[3], wi1[3], bsum[3], fcw[3];
#pragma unroll
    for (int jj = 0; jj < 3; ++jj) {
        const int j = 3 * g + jj;
        const bool v = (j < 20);
#pragma unroll
        for (int k = 0; k < 20; ++k)
            Wc[jj][k] = v ? W_hh[j * 20 + k] : 0.0f;
        wi0[jj]  = v ? W_ih[j * 2 + 0] : 0.0f;
        wi1[jj]  = v ? W_ih[j * 2 + 1] : 0.0f;
        bsum[jj] = v ? (b_ih[j] + b_hh[j]) : 0.0f;
        fcw[jj]  = v ? fc_w[j] : 0.0f;
    }

    float h[21];                              // h[0..19] live, h[20] pad
#pragma unroll
    for (int k = 0; k < 21; ++k) h[k] = 0.0f;
    float hn0 = 0.0f, hn1 = 0.0f, hn2 = 0.0f;

    const float* xrow = x + (size_t)row * (T_STEPS * 2);

    for (int t0 = 0; t0 < T_STEPS; t0 += 8) {
        // one coalesced 8B load per lane per 8 steps: lane g holds x[row][t0+g][:]
        const float2 xv = *(const float2*)(xrow + (size_t)(t0 + g) * 2);
#pragma unroll
        for (int s = 0; s < 8; ++s) {
            const float x0 = __shfl(xv.x, rowbase | s, 64);
            const float x1 = __shfl(xv.y, rowbase | s, 64);

            // acc_j = b_ih[j]+b_hh[j] + x0*W_ih[j,0] + x1*W_ih[j,1] + sum_k h[k]*W_hh[j,k]
            float a0 = fmaf(x1, wi1[0], fmaf(x0, wi0[0], bsum[0]));
            float a1 = fmaf(x1, wi1[1], fmaf(x0, wi0[1], bsum[1]));
            float a2 = fmaf(x1, wi1[2], fmaf(x0, wi0[2], bsum[2]));
#pragma unroll
            for (int k = 0; k < 20; ++k) {
                a0 = fmaf(h[k], Wc[0][k], a0);
                a1 = fmaf(h[k], Wc[1][k], a1);
                a2 = fmaf(h[k], Wc[2][k], a2);
            }
            hn0 = tanh_fast(a0);
            hn1 = tanh_fast(a1);
            hn2 = tanh_fast(a2);

            // broadcast blocks 0..6 (covers j = 0..20) to rebuild full h
#pragma unroll
            for (int b = 0; b < 7; ++b) {
                h[3 * b + 0] = __shfl(hn0, rowbase | b, 64);
                h[3 * b + 1] = __shfl(hn1, rowbase | b, 64);
                h[3 * b + 2] = __shfl(hn2, rowbase | b, 64);
            }
        }
    }

    // ---- epilogue ----
    // h_state: [1, B, H] flat at offset B_ROWS
#pragma unroll
    for (int jj = 0; jj < 3; ++jj) {
        const int j = 3 * g + jj;
        const float hv = (jj == 0) ? hn0 : (jj == 1) ? hn1 : hn2;
        if (j < 20) out[B_ROWS + (size_t)row * 20 + j] = hv;
    }
    // out[b] = sum_j h[j]*fc_w[j] + fc_b  (octet reduction; garbage lanes add 0)
    float p = hn0 * fcw[0] + hn1 * fcw[1] + hn2 * fcw[2];
    p += __shfl_xor(p, 1, 64);
    p += __shfl_xor(p, 2, 64);
    p += __shfl_xor(p, 4, 64);
    if (g == 0) out[row] = p + fc_b[0];
}

extern "C" void kernel_launch(void* const* d_in, const int* in_sizes, int n_in,
                              void* d_out, int out_size, void* d_ws, size_t ws_size,
                              hipStream_t stream) {
    const float* x    = (const float*)d_in[0];
    const float* W_ih = (const float*)d_in[1];
    const float* W_hh = (const float*)d_in[2];
    const float* b_ih = (const float*)d_in[3];
    const float* b_hh = (const float*)d_in[4];
    const float* fc_w = (const float*)d_in[5];
    const float* fc_b = (const float*)d_in[6];
    float* out = (float*)d_out;

    // 256 blocks x 256 threads = 65536 lanes = 8 lanes/row * 8192 rows
    rnn_fused<<<256, 256, 0, stream>>>(x, W_ih, W_hh, b_ih, b_hh, fc_w, fc_b, out);
}

// Round 2
// 607.277 us; speedup vs baseline: 1.4750x; 1.4750x over previous
//
#include <hip/hip_runtime.h>

// Tanh-RNN: B=8192, T=2048, I=2, H=20, FC(H->1) on last h.
// Round 2: 8 lanes/row, ONE WAVE PER BLOCK (64 thr), h exchanged through LDS
// (3x ds_write_b32 + 5x ds_read_b128 per step) instead of 21 ds_bpermute.
// DS pipe is in-order per wave -> write->read needs no barrier/waitcnt, only a
// compiler reordering fence (zero instructions). x register-double-buffered
// from global (same-cacheline loads, L1-absorbed), prefetched 1 chunk ahead.

#define T_STEPS 2048
#define B_ROWS  8192
#define NCHUNK  (T_STEPS / 8)

__device__ __forceinline__ float tanh_fast(float a) {
    // tanh(a) = 1 - 2/(exp(2a)+1); exp(2a) = exp2(a * 2*log2(e))
    float e = __builtin_amdgcn_exp2f(a * 2.8853900817779268f);
    float r = __builtin_amdgcn_rcpf(e + 1.0f);
    return fmaf(-2.0f, r, 1.0f);
}

// Compiler-level memory ordering fence, zero instructions. Hardware DS pipe
// processes a wave's LDS ops in issue order, so this is sufficient for
// intra-wave write->read (RAW) and read->write (WAR) on LDS.
#define LDS_FENCE() asm volatile("" ::: "memory")

__global__ __launch_bounds__(64) void rnn_fused(
    const float* __restrict__ x,      // [B, T, 2]
    const float* __restrict__ W_ih,   // [20, 2]
    const float* __restrict__ W_hh,   // [20, 20]
    const float* __restrict__ b_ih,   // [20]
    const float* __restrict__ b_hh,   // [20]
    const float* __restrict__ fc_w,   // [1, 20]
    const float* __restrict__ fc_b,   // [1]
    float* __restrict__ out)          // [8192] out, then [8192*20] h_state
{
    __shared__ __align__(16) float hbuf[8][24];  // 8 rows x padded-24 (96B stride)

    const int lane = threadIdx.x & 63;
    const int g    = lane & 7;        // j-group: owns j = 3g..3g+2
    const int r    = lane >> 3;       // row within block, 0..7
    const int row  = blockIdx.x * 8 + r;

    // ---- per-lane constants (zero for padded j >= 20) ----
    float Wc[3][20];
    float wi0[3], wi1[3], bsum[3];
#pragma unroll
    for (int jj = 0; jj < 3; ++jj) {
        const int j = 3 * g + jj;
        const bool v = (j < 20);
#pragma unroll
        for (int k = 0; k < 20; ++k)
            Wc[jj][k] = v ? W_hh[j * 20 + k] : 0.0f;
        wi0[jj]  = v ? W_ih[j * 2 + 0] : 0.0f;
        wi1[jj]  = v ? W_ih[j * 2 + 1] : 0.0f;
        bsum[jj] = v ? (b_ih[j] + b_hh[j]) : 0.0f;
    }

    const float2* xr = (const float2*)(x + (size_t)row * (T_STEPS * 2));

    // h carried in registers as 5 float4 (read back from LDS each step)
    float4 v0 = {0,0,0,0}, v1 = {0,0,0,0}, v2 = {0,0,0,0}, v3 = {0,0,0,0}, v4 = {0,0,0,0};
    float hn0 = 0.0f, hn1 = 0.0f, hn2 = 0.0f;

    float* hw = &hbuf[r][3 * g];      // this lane's write slot

    auto step = [&](float2 xs) {
        float a0 = fmaf(xs.y, wi1[0], fmaf(xs.x, wi0[0], bsum[0]));
        float a1 = fmaf(xs.y, wi1[1], fmaf(xs.x, wi0[1], bsum[1]));
        float a2 = fmaf(xs.y, wi1[2], fmaf(xs.x, wi0[2], bsum[2]));
#define KFMA(K, HK) \
        a0 = fmaf((HK), Wc[0][K], a0); \
        a1 = fmaf((HK), Wc[1][K], a1); \
        a2 = fmaf((HK), Wc[2][K], a2);
        KFMA(0,  v0.x) KFMA(1,  v0.y) KFMA(2,  v0.z) KFMA(3,  v0.w)
        KFMA(4,  v1.x) KFMA(5,  v1.y) KFMA(6,  v1.z) KFMA(7,  v1.w)
        KFMA(8,  v2.x) KFMA(9,  v2.y) KFMA(10, v2.z) KFMA(11, v2.w)
        KFMA(12, v3.x) KFMA(13, v3.y) KFMA(14, v3.z) KFMA(15, v3.w)
        KFMA(16, v4.x) KFMA(17, v4.y) KFMA(18, v4.z) KFMA(19, v4.w)
#undef KFMA
        hn0 = tanh_fast(a0);
        hn1 = tanh_fast(a1);
        hn2 = tanh_fast(a2);
        hw[0] = hn0;
        hw[1] = hn1;
        hw[2] = hn2;
        LDS_FENCE();                  // keep reads after writes (HW pipe is in-order)
        v0 = *(const float4*)&hbuf[r][0];
        v1 = *(const float4*)&hbuf[r][4];
        v2 = *(const float4*)&hbuf[r][8];
        v3 = *(const float4*)&hbuf[r][12];
        v4 = *(const float4*)&hbuf[r][16];
        LDS_FENCE();                  // keep next step's writes after these reads
    };

    // x double-buffer: prefetch one 8-step chunk ahead
    float2 xa[8], xb[8];
#pragma unroll
    for (int s = 0; s < 8; ++s) xa[s] = xr[s];

    for (int c = 0; c < NCHUNK / 2; ++c) {
        const float2* xn = xr + (size_t)(2 * c + 1) * 8;
#pragma unroll
        for (int s = 0; s < 8; ++s) xb[s] = xn[s];
#pragma unroll
        for (int s = 0; s < 8; ++s) step(xa[s]);
        if (c + 1 < NCHUNK / 2) {
            const float2* xm = xr + (size_t)(2 * c + 2) * 8;
#pragma unroll
            for (int s = 0; s < 8; ++s) xa[s] = xm[s];
        }
#pragma unroll
        for (int s = 0; s < 8; ++s) step(xb[s]);
    }

    // ---- epilogue ----
    // h_state: [1, B, H] flat at offset B_ROWS; each lane stores its own 3 j
    {
        const int j0 = 3 * g;
        float* hs = out + B_ROWS + (size_t)row * 20;
        if (j0 + 0 < 20) hs[j0 + 0] = hn0;
        if (j0 + 1 < 20) hs[j0 + 1] = hn1;
        if (j0 + 2 < 20) hs[j0 + 2] = hn2;
    }
    // FC on last h: every lane holds the full h_T in v0..v4; lane g==0 stores
    if (g == 0) {
        float p = fc_b[0];
        p = fmaf(v0.x, fc_w[0],  p); p = fmaf(v0.y, fc_w[1],  p);
        p = fmaf(v0.z, fc_w[2],  p); p = fmaf(v0.w, fc_w[3],  p);
        p = fmaf(v1.x, fc_w[4],  p); p = fmaf(v1.y, fc_w[5],  p);
        p = fmaf(v1.z, fc_w[6],  p); p = fmaf(v1.w, fc_w[7],  p);
        p = fmaf(v2.x, fc_w[8],  p); p = fmaf(v2.y, fc_w[9],  p);
        p = fmaf(v2.z, fc_w[10], p); p = fmaf(v2.w, fc_w[11], p);
        p = fmaf(v3.x, fc_w[12], p); p = fmaf(v3.y, fc_w[13], p);
        p = fmaf(v3.z, fc_w[14], p); p = fmaf(v3.w, fc_w[15], p);
        p = fmaf(v4.x, fc_w[16], p); p = fmaf(v4.y, fc_w[17], p);
        p = fmaf(v4.z, fc_w[18], p); p = fmaf(v4.w, fc_w[19], p);
        out[row] = p;
    }
}

extern "C" void kernel_launch(void* const* d_in, const int* in_sizes, int n_in,
                              void* d_out, int out_size, void* d_ws, size_t ws_size,
                              hipStream_t stream) {
    const float* x    = (const float*)d_in[0];
    const float* W_ih = (const float*)d_in[1];
    const float* W_hh = (const float*)d_in[2];
    const float* b_ih = (const float*)d_in[3];
    const float* b_hh = (const float*)d_in[4];
    const float* fc_w = (const float*)d_in[5];
    const float* fc_b = (const float*)d_in[6];
    float* out = (float*)d_out;

    // 1024 blocks x 64 threads = one wave per block, 8 rows per wave
    rnn_fused<<<1024, 64, 0, stream>>>(x, W_ih, W_hh, b_ih, b_hh, fc_w, fc_b, out);
}